// Round 3
// baseline (1945.598 us; speedup 1.0000x reference)
//
#include <hip/hip_runtime.h>

#define D 64

__device__ __forceinline__ float relu_f(float v) { return v > 0.f ? v : 0.f; }

// x[e][:] = fact_emb[edge_type[e]][:]
__global__ void k_gather(const int* __restrict__ et, const float* __restrict__ fe,
                         float* __restrict__ x, int E) {
    int u = blockIdx.x * blockDim.x + threadIdx.x;
    if (u >= E * 16) return;
    int e = u >> 4, q = u & 15;
    float4 v = reinterpret_cast<const float4*>(fe + (size_t)et[e] * D)[q];
    reinterpret_cast<float4*>(x + (size_t)e * D)[q] = v;
}

// ---------------- CSR build: histogram + scan + permute ----------------

__global__ void k_hist(const int* __restrict__ ac, int* __restrict__ cnt, int T) {
    int t = blockIdx.x * blockDim.x + threadIdx.x;
    if (t < T) atomicAdd(&cnt[ac[t]], 1);
}

__global__ __launch_bounds__(256) void k_scanA(const int* __restrict__ cnt,
        int* __restrict__ localExcl, int* __restrict__ blockSums, int E) {
    __shared__ int ls[256];
    const int tid = threadIdx.x;
    int base = blockIdx.x * 1024 + tid * 4;
    int a0 = 0, a1 = 0, a2 = 0, a3 = 0;
    if (base + 3 < E) {
        int4 v = *reinterpret_cast<const int4*>(cnt + base);
        a0 = v.x; a1 = v.y; a2 = v.z; a3 = v.w;
    } else {
        if (base + 0 < E) a0 = cnt[base + 0];
        if (base + 1 < E) a1 = cnt[base + 1];
        if (base + 2 < E) a2 = cnt[base + 2];
        if (base + 3 < E) a3 = cnt[base + 3];
    }
    int tsum = a0 + a1 + a2 + a3;
    ls[tid] = tsum;
    __syncthreads();
    for (int off = 1; off < 256; off <<= 1) {
        int v = (tid >= off) ? ls[tid - off] : 0;
        __syncthreads();
        ls[tid] += v;
        __syncthreads();
    }
    int excl = ls[tid] - tsum;
    if (tid == 255) blockSums[blockIdx.x] = ls[255];
    if (base + 3 < E) {
        int4 o = make_int4(excl, excl + a0, excl + a0 + a1, excl + a0 + a1 + a2);
        *reinterpret_cast<int4*>(localExcl + base) = o;
    } else {
        int run = excl;
        if (base + 0 < E) { localExcl[base + 0] = run; run += a0; }
        if (base + 1 < E) { localExcl[base + 1] = run; run += a1; }
        if (base + 2 < E) { localExcl[base + 2] = run; run += a2; }
        if (base + 3 < E) { localExcl[base + 3] = run; }
    }
}

__global__ __launch_bounds__(256) void k_scanB(int* __restrict__ blockSums, int n) {
    __shared__ int ls[256];
    const int tid = threadIdx.x;
    int v = (tid < n) ? blockSums[tid] : 0;
    ls[tid] = v;
    __syncthreads();
    for (int off = 1; off < 256; off <<= 1) {
        int w = (tid >= off) ? ls[tid - off] : 0;
        __syncthreads();
        ls[tid] += w;
        __syncthreads();
    }
    if (tid < n) blockSums[tid] = ls[tid] - v;   // exclusive
}

__global__ void k_scanC(int* __restrict__ startArr, const int* __restrict__ blockSums,
                        int* __restrict__ cursor, int E) {
    int i = blockIdx.x * blockDim.x + threadIdx.x;
    if (i < E) {
        int s = startArr[i] + blockSums[i >> 10];
        startArr[i] = s;
        cursor[i] = s;
    }
}

__global__ void k_permute(const int* __restrict__ ab, const int* __restrict__ bc,
                          const int* __restrict__ ac, int* __restrict__ cursor,
                          int2* __restrict__ tri, int T) {
    int t = blockIdx.x * blockDim.x + threadIdx.x;
    if (t >= T) return;
    int pos = atomicAdd(&cursor[ac[t]], 1);
    tri[pos] = make_int2(ab[t], bc[t]);
}

// ---------------- fused message-gather + linear + relu ----------------
// one wave per edge (grid-strided): acc[lane] = sum_t xin[ab][lane]*xin[bc][lane]
// then xout[e][lane] = relu( sum_k readlane(acc,k) * W[k][lane] + b[lane] )
__global__ __launch_bounds__(256) void k_msg_linear(const int* __restrict__ startArr,
        const int* __restrict__ cnt, const int2* __restrict__ tri,
        const float* __restrict__ xin, const float* __restrict__ W,
        const float* __restrict__ b, float* __restrict__ xout, int E, int nwaves) {
    const int lane = threadIdx.x & 63;
    const int wid = (blockIdx.x * blockDim.x + threadIdx.x) >> 6;

    float w[D];
    #pragma unroll
    for (int k = 0; k < D; ++k) w[k] = W[k * D + lane];
    const float bias = b[lane];

    for (int e = wid; e < E; e += nwaves) {
        int s = startArr[e], c = cnt[e];
        float acc = 0.f;
        int i = 0;
        for (; i + 1 < c; i += 2) {
            int2 p0 = tri[s + i];
            int2 p1 = tri[s + i + 1];
            float a0 = xin[(size_t)p0.x * D + lane] * xin[(size_t)p0.y * D + lane];
            float a1 = xin[(size_t)p1.x * D + lane] * xin[(size_t)p1.y * D + lane];
            acc += a0 + a1;
        }
        if (i < c) {
            int2 p = tri[s + i];
            acc += xin[(size_t)p.x * D + lane] * xin[(size_t)p.y * D + lane];
        }
        float o0 = bias, o1 = 0.f;
        int ai = __builtin_bit_cast(int, acc);
        #pragma unroll
        for (int k = 0; k < D; k += 2) {
            o0 += __builtin_bit_cast(float, __builtin_amdgcn_readlane(ai, k)) * w[k];
            o1 += __builtin_bit_cast(float, __builtin_amdgcn_readlane(ai, k + 1)) * w[k + 1];
        }
        xout[(size_t)e * D + lane] = relu_f(o0 + o1);
    }
}

// ---------------- final MLP ----------------
// out[e] = relu(concat(x[e], fe[et[e]]) @ W1 + b1) @ W2 + b2
#define MSTRIDE 132
__global__ __launch_bounds__(512) void k_mlp(const float* __restrict__ x,
        const int* __restrict__ et, const float* __restrict__ fe,
        const float* __restrict__ W1, const float* __restrict__ b1,
        const float* __restrict__ W2, const float* __restrict__ b2,
        float* __restrict__ out, int E) {
    __shared__ float Wl[64 * 128];        // 32 KB (staged per k-half)
    __shared__ float fl[64 * MSTRIDE];    // 33.8 KB, row-major [r][k]
    __shared__ float b1l[128];
    __shared__ float W2l[128];
    const int tid = threadIdx.x;
    const int row0 = blockIdx.x * 64;

    if (tid < 128) { b1l[tid] = b1[tid]; W2l[tid] = W2[tid]; }

    for (int i = tid; i < 2048; i += 512) {
        int r = i >> 5, q = i & 31;
        int row = row0 + r;
        float4 v = make_float4(0.f, 0.f, 0.f, 0.f);
        if (row < E) {
            if (q < 16)
                v = reinterpret_cast<const float4*>(x + (size_t)row * D)[q];
            else
                v = reinterpret_cast<const float4*>(fe + (size_t)et[row] * D)[q - 16];
        }
        *reinterpret_cast<float4*>(&fl[r * MSTRIDE + q * 4]) = v;
    }

    const int jt = tid & 31;
    const int j0 = jt * 4;
    const int r0 = (tid >> 5) * 4;
    float acc[4][4];
    #pragma unroll
    for (int i = 0; i < 4; ++i)
        #pragma unroll
        for (int j = 0; j < 4; ++j) acc[i][j] = 0.f;

    #pragma unroll
    for (int h = 0; h < 2; ++h) {
        __syncthreads();
        for (int i = tid; i < 2048; i += 512)
            reinterpret_cast<float4*>(Wl)[i] =
                reinterpret_cast<const float4*>(W1 + (size_t)h * 64 * 128)[i];
        __syncthreads();

        for (int k4 = 0; k4 < 16; ++k4) {
            float4 f[4];
            #pragma unroll
            for (int i = 0; i < 4; ++i)
                f[i] = *reinterpret_cast<const float4*>(
                          &fl[(r0 + i) * MSTRIDE + h * 64 + k4 * 4]);
            #pragma unroll
            for (int kk = 0; kk < 4; ++kk) {
                float4 w = *reinterpret_cast<const float4*>(&Wl[(k4 * 4 + kk) * 128 + j0]);
                float wa[4] = {w.x, w.y, w.z, w.w};
                float fa[4];
                fa[0] = (kk == 0) ? f[0].x : (kk == 1) ? f[0].y : (kk == 2) ? f[0].z : f[0].w;
                fa[1] = (kk == 0) ? f[1].x : (kk == 1) ? f[1].y : (kk == 2) ? f[1].z : f[1].w;
                fa[2] = (kk == 0) ? f[2].x : (kk == 1) ? f[2].y : (kk == 2) ? f[2].z : f[2].w;
                fa[3] = (kk == 0) ? f[3].x : (kk == 1) ? f[3].y : (kk == 2) ? f[3].z : f[3].w;
                #pragma unroll
                for (int i = 0; i < 4; ++i)
                    #pragma unroll
                    for (int j = 0; j < 4; ++j) acc[i][j] += fa[i] * wa[j];
            }
        }
    }

    float4 bv = *reinterpret_cast<const float4*>(&b1l[j0]);
    float4 w2 = *reinterpret_cast<const float4*>(&W2l[j0]);
    float bias2 = b2[0];
    #pragma unroll
    for (int i = 0; i < 4; ++i) {
        float h0 = relu_f(acc[i][0] + bv.x);
        float h1 = relu_f(acc[i][1] + bv.y);
        float h2 = relu_f(acc[i][2] + bv.z);
        float h3 = relu_f(acc[i][3] + bv.w);
        float p = h0 * w2.x + h1 * w2.y + h2 * w2.z + h3 * w2.w;
        #pragma unroll
        for (int m = 1; m < 32; m <<= 1) p += __shfl_xor(p, m, 64);
        if (jt == 0) {
            int row = row0 + r0 + i;
            if (row < E) out[row] = p + bias2;
        }
    }
}

extern "C" void kernel_launch(void* const* d_in, const int* in_sizes, int n_in,
                              void* d_out, int out_size, void* d_ws, size_t ws_size,
                              hipStream_t stream) {
    const int*   edge_type = (const int*)d_in[0];
    const int*   ab        = (const int*)d_in[1];
    const int*   bc        = (const int*)d_in[2];
    const int*   ac        = (const int*)d_in[3];
    const float* fe        = (const float*)d_in[4];
    const float* W1        = (const float*)d_in[5];
    const float* b1        = (const float*)d_in[6];
    const float* W2        = (const float*)d_in[7];
    const float* b2        = (const float*)d_in[8];
    const float* mW1       = (const float*)d_in[9];
    const float* mb1       = (const float*)d_in[10];
    const float* mW2       = (const float*)d_in[11];
    const float* mb2       = (const float*)d_in[12];

    const int E = in_sizes[0];
    const int T = in_sizes[1];
    float* out = (float*)d_out;

    // workspace layout
    char* p = (char*)d_ws;
    float* xa   = (float*)p;   p += (size_t)E * D * sizeof(float);
    float* xb   = (float*)p;   p += (size_t)E * D * sizeof(float);
    int* cnt    = (int*)p;     p += (size_t)E * sizeof(int);
    int* startA = (int*)p;     p += (size_t)E * sizeof(int);
    int* cursor = (int*)p;     p += (size_t)E * sizeof(int);
    int* bsums  = (int*)p;     p += 256 * sizeof(int);
    int2* tri   = (int2*)p;    p += (size_t)T * sizeof(int2);

    const int nblkA = (E + 1023) / 1024;

    // CSR of triangles keyed by ac (reused by both layers)
    hipMemsetAsync(cnt, 0, (size_t)E * sizeof(int), stream);
    k_hist<<<(T + 255) / 256, 256, 0, stream>>>(ac, cnt, T);
    k_scanA<<<nblkA, 256, 0, stream>>>(cnt, startA, bsums, E);
    k_scanB<<<1, 256, 0, stream>>>(bsums, nblkA);
    k_scanC<<<(E + 255) / 256, 256, 0, stream>>>(startA, bsums, cursor, E);
    k_permute<<<(T + 255) / 256, 256, 0, stream>>>(ab, bc, ac, cursor, tri, T);

    k_gather<<<(E * 16 + 255) / 256, 256, 0, stream>>>(edge_type, fe, xa, E);

    const int MSG_BLOCKS = 1280;
    const int nwaves = MSG_BLOCKS * 256 / 64;
    // layer 1: xa -> xb ; layer 2: xb -> xa
    k_msg_linear<<<MSG_BLOCKS, 256, 0, stream>>>(startA, cnt, tri, xa, W1, b1, xb, E, nwaves);
    k_msg_linear<<<MSG_BLOCKS, 256, 0, stream>>>(startA, cnt, tri, xb, W2, b2, xa, E, nwaves);

    k_mlp<<<(E + 63) / 64, 512, 0, stream>>>(xa, edge_type, fe, mW1, mb1, mW2, mb2, out, E);
}

// Round 4
// 263.880 us; speedup vs baseline: 7.3730x; 7.3730x over previous
//
#include <hip/hip_runtime.h>

#define D 64

__device__ __forceinline__ float relu_f(float v) { return v > 0.f ? v : 0.f; }

// x[e][:] = fact_emb[edge_type[e]][:]
__global__ void k_gather(const int* __restrict__ et, const float* __restrict__ fe,
                         float* __restrict__ x, int E) {
    int u = blockIdx.x * blockDim.x + threadIdx.x;
    if (u >= E * 16) return;
    int e = u >> 4, q = u & 15;
    float4 v = reinterpret_cast<const float4*>(fe + (size_t)et[e] * D)[q];
    reinterpret_cast<float4*>(x + (size_t)e * D)[q] = v;
}

// ---------------- CSR build: histogram + scan + permute ----------------

__global__ void k_hist(const int* __restrict__ ac, int* __restrict__ cnt, int T) {
    int t = blockIdx.x * blockDim.x + threadIdx.x;
    if (t < T) atomicAdd(&cnt[ac[t]], 1);
}

__global__ __launch_bounds__(256) void k_scanA(const int* __restrict__ cnt,
        int* __restrict__ localExcl, int* __restrict__ blockSums, int E) {
    __shared__ int ls[256];
    const int tid = threadIdx.x;
    int base = blockIdx.x * 1024 + tid * 4;
    int a0 = 0, a1 = 0, a2 = 0, a3 = 0;
    if (base + 3 < E) {
        int4 v = *reinterpret_cast<const int4*>(cnt + base);
        a0 = v.x; a1 = v.y; a2 = v.z; a3 = v.w;
    } else {
        if (base + 0 < E) a0 = cnt[base + 0];
        if (base + 1 < E) a1 = cnt[base + 1];
        if (base + 2 < E) a2 = cnt[base + 2];
        if (base + 3 < E) a3 = cnt[base + 3];
    }
    int tsum = a0 + a1 + a2 + a3;
    ls[tid] = tsum;
    __syncthreads();
    for (int off = 1; off < 256; off <<= 1) {
        int v = (tid >= off) ? ls[tid - off] : 0;
        __syncthreads();
        ls[tid] += v;
        __syncthreads();
    }
    int excl = ls[tid] - tsum;
    if (tid == 255) blockSums[blockIdx.x] = ls[255];
    if (base + 3 < E) {
        int4 o = make_int4(excl, excl + a0, excl + a0 + a1, excl + a0 + a1 + a2);
        *reinterpret_cast<int4*>(localExcl + base) = o;
    } else {
        int run = excl;
        if (base + 0 < E) { localExcl[base + 0] = run; run += a0; }
        if (base + 1 < E) { localExcl[base + 1] = run; run += a1; }
        if (base + 2 < E) { localExcl[base + 2] = run; run += a2; }
        if (base + 3 < E) { localExcl[base + 3] = run; }
    }
}

__global__ __launch_bounds__(256) void k_scanB(int* __restrict__ blockSums, int n) {
    __shared__ int ls[256];
    const int tid = threadIdx.x;
    int v = (tid < n) ? blockSums[tid] : 0;
    ls[tid] = v;
    __syncthreads();
    for (int off = 1; off < 256; off <<= 1) {
        int w = (tid >= off) ? ls[tid - off] : 0;
        __syncthreads();
        ls[tid] += w;
        __syncthreads();
    }
    if (tid < n) blockSums[tid] = ls[tid] - v;   // exclusive
}

__global__ void k_scanC(int* __restrict__ startArr, const int* __restrict__ blockSums,
                        int* __restrict__ cursor, int E) {
    int i = blockIdx.x * blockDim.x + threadIdx.x;
    if (i < E) {
        int s = startArr[i] + blockSums[i >> 10];
        startArr[i] = s;
        cursor[i] = s;
    }
}

__global__ void k_permute(const int* __restrict__ ab, const int* __restrict__ bc,
                          const int* __restrict__ ac, int* __restrict__ cursor,
                          int2* __restrict__ tri, int T) {
    int t = blockIdx.x * blockDim.x + threadIdx.x;
    if (t >= T) return;
    int pos = atomicAdd(&cursor[ac[t]], 1);
    tri[pos] = make_int2(ab[t], bc[t]);
}

// ---------------- fused message-gather + linear + relu ----------------
// one wave per edge (grid-strided): acc[lane] = sum_t xin[ab][lane]*xin[bc][lane]
// then xout[e][lane] = relu( sum_k readlane(acc,k) * W[k][lane] + b[lane] )
__global__ __launch_bounds__(256) void k_msg_linear(const int* __restrict__ startArr,
        const int* __restrict__ cnt, const int2* __restrict__ tri,
        const float* __restrict__ xin, const float* __restrict__ W,
        const float* __restrict__ b, float* __restrict__ xout, int E, int nwaves) {
    const int lane = threadIdx.x & 63;
    const int wid = (blockIdx.x * blockDim.x + threadIdx.x) >> 6;

    float w[D];
    #pragma unroll
    for (int k = 0; k < D; ++k) w[k] = W[k * D + lane];
    const float bias = b[lane];

    for (int e = wid; e < E; e += nwaves) {
        int s = startArr[e], c = cnt[e];
        float acc = 0.f;
        int i = 0;
        for (; i + 1 < c; i += 2) {
            int2 p0 = tri[s + i];
            int2 p1 = tri[s + i + 1];
            float a0 = xin[(size_t)p0.x * D + lane] * xin[(size_t)p0.y * D + lane];
            float a1 = xin[(size_t)p1.x * D + lane] * xin[(size_t)p1.y * D + lane];
            acc += a0 + a1;
        }
        if (i < c) {
            int2 p = tri[s + i];
            acc += xin[(size_t)p.x * D + lane] * xin[(size_t)p.y * D + lane];
        }
        float o0 = bias, o1 = 0.f;
        int ai = __builtin_bit_cast(int, acc);
        #pragma unroll
        for (int k = 0; k < D; k += 2) {
            o0 += __builtin_bit_cast(float, __builtin_amdgcn_readlane(ai, k)) * w[k];
            o1 += __builtin_bit_cast(float, __builtin_amdgcn_readlane(ai, k + 1)) * w[k + 1];
        }
        xout[(size_t)e * D + lane] = relu_f(o0 + o1);
    }
}

// ---------------- final MLP ----------------
// out[e] = relu(concat(x[e], fe[et[e]]) @ W1 + b1) @ W2 + b2
// Round-2 compute structure verbatim (fT transposed, VGPR-light), but:
//  - W1 staged in two 32KB halves -> LDS ~67KB -> 2 blocks/CU
//  - fT stride 65 -> staging-write conflicts 16-way -> 4-way
#define MPAD 65
__global__ __launch_bounds__(512) void k_mlp(const float* __restrict__ x,
        const int* __restrict__ et, const float* __restrict__ fe,
        const float* __restrict__ W1, const float* __restrict__ b1,
        const float* __restrict__ W2, const float* __restrict__ b2,
        float* __restrict__ out, int E) {
    __shared__ float Wl[64 * 128];      // 32 KB, one k-half of W1
    __shared__ float fT[128 * MPAD];    // 33.3 KB, fT[k][r]
    __shared__ float b1l[128];
    __shared__ float W2l[128];
    const int tid = threadIdx.x;
    const int row0 = blockIdx.x * 64;

    if (tid < 128) { b1l[tid] = b1[tid]; W2l[tid] = W2[tid]; }

    // stage features transposed: k<64 from x, k>=64 from fe[et[row]]
    for (int i = tid; i < 2048; i += 512) {
        int r = i >> 5, q = i & 31;
        int row = row0 + r;
        float4 v = make_float4(0.f, 0.f, 0.f, 0.f);
        if (row < E) {
            if (q < 16)
                v = reinterpret_cast<const float4*>(x + (size_t)row * D)[q];
            else
                v = reinterpret_cast<const float4*>(fe + (size_t)et[row] * D)[q - 16];
        }
        int kb = q * 4;   // q<16 -> k 0..63 ; q>=16 -> k 64..127
        fT[(kb + 0) * MPAD + r] = v.x;
        fT[(kb + 1) * MPAD + r] = v.y;
        fT[(kb + 2) * MPAD + r] = v.z;
        fT[(kb + 3) * MPAD + r] = v.w;
    }

    const int jt = tid & 31;
    const int j0 = jt * 4;
    const int r0 = (tid >> 5) * 4;
    float acc[4][4];
    #pragma unroll
    for (int i = 0; i < 4; ++i)
        #pragma unroll
        for (int j = 0; j < 4; ++j) acc[i][j] = 0.f;

    for (int h = 0; h < 2; ++h) {
        __syncthreads();   // h=0: fT ready barrier; h=1: Wl readers done
        for (int i = tid; i < 2048; i += 512)
            reinterpret_cast<float4*>(Wl)[i] =
                reinterpret_cast<const float4*>(W1 + (size_t)h * 64 * 128)[i];
        __syncthreads();

        #pragma unroll 8
        for (int k = 0; k < 64; ++k) {
            float4 f = *reinterpret_cast<const float4*>(&fT[(h * 64 + k) * MPAD + r0]);
            float4 w = *reinterpret_cast<const float4*>(&Wl[k * 128 + j0]);
            float fa[4] = {f.x, f.y, f.z, f.w};
            float wa[4] = {w.x, w.y, w.z, w.w};
            #pragma unroll
            for (int i = 0; i < 4; ++i)
                #pragma unroll
                for (int j = 0; j < 4; ++j) acc[i][j] += fa[i] * wa[j];
        }
    }

    float4 bv = *reinterpret_cast<const float4*>(&b1l[j0]);
    float4 w2 = *reinterpret_cast<const float4*>(&W2l[j0]);
    float bias2 = b2[0];
    #pragma unroll
    for (int i = 0; i < 4; ++i) {
        float h0 = relu_f(acc[i][0] + bv.x);
        float h1 = relu_f(acc[i][1] + bv.y);
        float h2 = relu_f(acc[i][2] + bv.z);
        float h3 = relu_f(acc[i][3] + bv.w);
        float p = h0 * w2.x + h1 * w2.y + h2 * w2.z + h3 * w2.w;
        #pragma unroll
        for (int m = 1; m < 32; m <<= 1) p += __shfl_xor(p, m, 64);
        if (jt == 0) {
            int row = row0 + r0 + i;
            if (row < E) out[row] = p + bias2;
        }
    }
}

extern "C" void kernel_launch(void* const* d_in, const int* in_sizes, int n_in,
                              void* d_out, int out_size, void* d_ws, size_t ws_size,
                              hipStream_t stream) {
    const int*   edge_type = (const int*)d_in[0];
    const int*   ab        = (const int*)d_in[1];
    const int*   bc        = (const int*)d_in[2];
    const int*   ac        = (const int*)d_in[3];
    const float* fe        = (const float*)d_in[4];
    const float* W1        = (const float*)d_in[5];
    const float* b1        = (const float*)d_in[6];
    const float* W2        = (const float*)d_in[7];
    const float* b2        = (const float*)d_in[8];
    const float* mW1       = (const float*)d_in[9];
    const float* mb1       = (const float*)d_in[10];
    const float* mW2       = (const float*)d_in[11];
    const float* mb2       = (const float*)d_in[12];

    const int E = in_sizes[0];
    const int T = in_sizes[1];
    float* out = (float*)d_out;

    // workspace layout
    char* p = (char*)d_ws;
    float* xa   = (float*)p;   p += (size_t)E * D * sizeof(float);
    float* xb   = (float*)p;   p += (size_t)E * D * sizeof(float);
    int* cnt    = (int*)p;     p += (size_t)E * sizeof(int);
    int* startA = (int*)p;     p += (size_t)E * sizeof(int);
    int* cursor = (int*)p;     p += (size_t)E * sizeof(int);
    int* bsums  = (int*)p;     p += 256 * sizeof(int);
    int2* tri   = (int2*)p;    p += (size_t)T * sizeof(int2);

    const int nblkA = (E + 1023) / 1024;

    // CSR of triangles keyed by ac (reused by both layers)
    hipMemsetAsync(cnt, 0, (size_t)E * sizeof(int), stream);
    k_hist<<<(T + 255) / 256, 256, 0, stream>>>(ac, cnt, T);
    k_scanA<<<nblkA, 256, 0, stream>>>(cnt, startA, bsums, E);
    k_scanB<<<1, 256, 0, stream>>>(bsums, nblkA);
    k_scanC<<<(E + 255) / 256, 256, 0, stream>>>(startA, bsums, cursor, E);
    k_permute<<<(T + 255) / 256, 256, 0, stream>>>(ab, bc, ac, cursor, tri, T);

    k_gather<<<(E * 16 + 255) / 256, 256, 0, stream>>>(edge_type, fe, xa, E);

    const int MSG_BLOCKS = 1280;
    const int nwaves = MSG_BLOCKS * 256 / 64;
    // layer 1: xa -> xb ; layer 2: xb -> xa
    k_msg_linear<<<MSG_BLOCKS, 256, 0, stream>>>(startA, cnt, tri, xa, W1, b1, xb, E, nwaves);
    k_msg_linear<<<MSG_BLOCKS, 256, 0, stream>>>(startA, cnt, tri, xb, W2, b2, xa, E, nwaves);

    k_mlp<<<(E + 63) / 64, 512, 0, stream>>>(xa, edge_type, fe, mW1, mb1, mW2, mb2, out, E);
}